// Round 5
// baseline (301.505 us; speedup 1.0000x reference)
//
#include <hip/hip_runtime.h>

#define HH 512
#define WW 512
#define PD 544                          // 512 + 2*16
#define PADN (3 * PD * PD)              // 887808 bf16 elements
#define OUTN (3 * HH * WW)
#define NB 128
#define KSTR 16384                      // 128*128 floats between taps

// ---------------- pad + out-zero: fp32 img -> bf16 edge-padded ----------------
__global__ __launch_bounds__(256) void pad_kernel(const float* __restrict__ img,
                                                  unsigned short* __restrict__ gpad,
                                                  float* __restrict__ out) {
    int idx = blockIdx.x * 256 + threadIdx.x;
    if (idx < OUTN) out[idx] = 0.0f;           // zero the atomic target
    if (idx >= PADN) return;
    int c  = idx / (PD * PD);
    int r  = idx - c * (PD * PD);
    int py = r / PD;
    int px = r - py * PD;
    int iy = min(max(py - 16, 0), HH - 1);
    int ix = min(max(px - 16, 0), WW - 1);
    union { float f; unsigned u; } v;
    v.f = img[(c * HH + iy) * WW + ix];
    unsigned u = v.u + 0x7FFFu + ((v.u >> 16) & 1u);   // RNE bf16
    gpad[idx] = (unsigned short)(u >> 16);
}

// ---- async global->LDS (wave-uniform LDS base; HW puts lane i at base+i*size) ----
__device__ __forceinline__ void async4(const float* g, float* l) {
    __builtin_amdgcn_global_load_lds((const __attribute__((address_space(1))) void*)g,
                                     (__attribute__((address_space(3))) void*)l, 4, 0, 0);
}
__device__ __forceinline__ void async16u(const unsigned short* g, unsigned short* l) {
    __builtin_amdgcn_global_load_lds((const __attribute__((address_space(1))) void*)g,
                                     (__attribute__((address_space(3))) void*)l, 16, 0, 0);
}
__device__ __forceinline__ float bflo(unsigned d) { union { unsigned u; float f; } x; x.u = d << 16;         return x.f; }
__device__ __forceinline__ float bfhi(unsigned d) { union { unsigned u; float f; } x; x.u = d & 0xFFFF0000u; return x.f; }

// ---------------- main kernel ----------------
// Grid = 4 u-chunks x 128 h x 2 wt = 1024 blocks of 128 thr (2 waves).
// Wave = dy-pair (0,1) or (2,3); lane = wb. Lane owns 2dy x 3c x 4oj = 24 accs.
// Iterate over image rows r: BOTH dy of the pair read the same row window
// (27 b64 serves 24x33 FMAs); dy_even uses weight row u=ua+t read fresh from
// LDS; dy_odd uses u-1 kept in registers from last iter (unroll-2 ring wA/wB,
// all constant-indexed). Weight LDS double-buffered; image rows in a 4-slot
// ring shared by both pairs (pair1 runs 2 rows ahead, each row staged once).
// Wave0 stages weights, wave1 stages the one new image row per iter; sync =
// own-stage vmcnt(0) + one s_barrier per iter (stages get a full iter to land).
// 8 waves/CU, LDS/CU-iter ~ VALU/SIMD-iter -> balanced near the 11us VALU floor.
__global__ __launch_bounds__(128, 3) void reblur_kernel(const unsigned short* __restrict__ gpad,
                                                        const float* __restrict__ Kern,
                                                        float* __restrict__ out) {
    __shared__ float s_w[2][33][64];            // 16.9 KB
    __shared__ unsigned short s_img[4][3][296]; // 7.1 KB

    const int lane   = threadIdx.x & 63;
    const int pairId = threadIdx.x >> 6;        // 0 or 1 (wave id)
    const int d0     = 2 * pairId;              // first dy of my pair
    const int uq     = blockIdx.x >> 8;         // u-chunk 0..3
    const int bb     = blockIdx.x & 255;
    const int h      = bb >> 1;                 // 0..127
    const int wt     = bb & 1;                  // 0..1
    const int ua     = (uq == 0) ? 0 : (1 + 8 * uq);   // chunk start: 0,9,17,25
    const int n      = (uq == 0) ? 9 : 8;              // chunk length
    const int kofs   = h * NB + wt * 64 + lane;
    const int rbase  = 4 * h + ua;              // first padded row this block touches

    // ---- prologue: wave0 stages weight row ua; wave1 stages img rows rbase..rbase+2 ----
    if (pairId == 0) {
#pragma unroll
        for (int v = 0; v < 33; ++v)
            async4(Kern + ((ua * 33 + v) * KSTR + kofs), &s_w[0][v][0]);
    } else if (lane < 36) {
#pragma unroll
        for (int rr = 0; rr < 3; ++rr)
#pragma unroll
            for (int c = 0; c < 3; ++c)
                async16u(gpad + ((size_t)(c * PD + rbase + rr) * PD + 256 * wt) + 8 * lane,
                         &s_img[(rbase + rr) & 3][c][0]);
    }

    float wA[33], wB[33];
    float accE[3][4], accO[3][4];
#pragma unroll
    for (int c = 0; c < 3; ++c)
#pragma unroll
        for (int oj = 0; oj < 4; ++oj) { accE[c][oj] = 0.f; accO[c][oj] = 0.f; }

    // one pipelined iteration; par is 0/1 compile-time after inlining,
    // wnew/wold alternate between wA/wB (static register ring)
    auto body = [&](int t, int par, float (&wnew)[33], float (&wold)[33]) {
        asm volatile("s_waitcnt vmcnt(0)" ::: "memory");   // my stages from t-1 landed
        __builtin_amdgcn_s_barrier();                      // partner's too; prev reads done
        asm volatile("" ::: "memory");

        const bool doE = (t < n);                          // dy_even active (u=ua+t)
        const bool doO = (t > 0);                          // dy_odd active (u=ua+t-1)

        // ---- issue next iter's stages (fire-and-forget) ----
        if (doE) {
            if (pairId == 0) {
                const int un = ua + t + 1;
                if (t + 1 < n) {
#pragma unroll
                    for (int v = 0; v < 33; ++v)
                        async4(Kern + ((un * 33 + v) * KSTR + kofs), &s_w[par ^ 1][v][0]);
                }
            } else if (lane < 36) {
                const int r = rbase + t + 3;               // max rbase+n+2 <= 543
#pragma unroll
                for (int c = 0; c < 3; ++c)
                    async16u(gpad + ((size_t)(c * PD + r) * PD + 256 * wt) + 8 * lane,
                             &s_img[r & 3][c][0]);
            }
        }

        // ---- fresh weight row for dy_even ----
        if (doE) {
#pragma unroll
            for (int v = 0; v < 33; ++v) wnew[v] = s_w[par][v][lane];
        }

        // ---- window row for this pair: r = rbase + d0 + t, shared by both dy ----
        const int slot = (rbase + d0 + t) & 3;
#pragma unroll
        for (int c = 0; c < 3; ++c) {
            float wf[36];
            const unsigned short* sp = &s_img[slot][c][4 * lane];
#pragma unroll
            for (int j = 0; j < 9; ++j) {
                const uint2 dd = *(const uint2*)(sp + 4 * j);
                wf[4 * j + 0] = bflo(dd.x);
                wf[4 * j + 1] = bfhi(dd.x);
                wf[4 * j + 2] = bflo(dd.y);
                wf[4 * j + 3] = bfhi(dd.y);
            }
            if (doE) {
#pragma unroll
                for (int v = 0; v < 33; ++v)
#pragma unroll
                    for (int oj = 0; oj < 4; ++oj)
                        accE[c][oj] = fmaf(wf[v + oj], wnew[v], accE[c][oj]);
            }
            if (doO) {
#pragma unroll
                for (int v = 0; v < 33; ++v)
#pragma unroll
                    for (int oj = 0; oj < 4; ++oj)
                        accO[c][oj] = fmaf(wf[v + oj], wold[v], accO[c][oj]);
            }
        }
    };

#pragma unroll 1
    for (int t2 = 0; t2 <= n; t2 += 2) {
        body(t2, 0, wA, wB);
        if (t2 + 1 <= n) body(t2 + 1, 1, wB, wA);
    }

    // ---- epilogue: 4 u-chunks accumulate into the zeroed output ----
    const int xb = 4 * (wt * 64 + lane);
#pragma unroll
    for (int c = 0; c < 3; ++c) {
        float* opE = out + (size_t)(c * HH + 4 * h + d0) * WW + xb;
        float* opO = opE + WW;
#pragma unroll
        for (int oj = 0; oj < 4; ++oj) {
            atomicAdd(opE + oj, accE[c][oj]);
            atomicAdd(opO + oj, accO[c][oj]);
        }
    }
}

// ---------------- fallback (ws too small): naive but correct ----------------
__global__ __launch_bounds__(256) void reblur_naive(const float* __restrict__ img,
                                                    const float* __restrict__ Kern,
                                                    float* __restrict__ out) {
    const int lane = threadIdx.x & 63;
    const int dy   = threadIdx.x >> 6;
    const int c    = blockIdx.x >> 8;
    const int bb   = blockIdx.x & 255;
    const int h    = bb >> 1;
    const int wt   = bb & 1;
    const int wb   = wt * 64 + lane;
    const int y    = 4 * h + dy;

    float acc[4] = {0.f, 0.f, 0.f, 0.f};
    const float* kb = Kern + h * NB + wb;
#pragma unroll 1
    for (int u = 0; u < 33; ++u) {
        const int iy = min(max(y + u - 16, 0), HH - 1);
        float row[36];
#pragma unroll
        for (int e = 0; e < 36; ++e) {
            const int ix = min(max(4 * wb + e - 16, 0), WW - 1);
            row[e]       = img[(c * HH + iy) * WW + ix];
        }
#pragma unroll
        for (int v = 0; v < 33; ++v) {
            const float w = kb[(u * 33 + v) * KSTR];
#pragma unroll
            for (int oj = 0; oj < 4; ++oj)
                acc[oj] = fmaf(row[v + oj], w, acc[oj]);
        }
    }
    float4 o;
    o.x = acc[0]; o.y = acc[1]; o.z = acc[2]; o.w = acc[3];
    *reinterpret_cast<float4*>(out + (size_t)(c * HH + y) * WW + 4 * wb) = o;
}

extern "C" void kernel_launch(void* const* d_in, const int* in_sizes, int n_in,
                              void* d_out, int out_size, void* d_ws, size_t ws_size,
                              hipStream_t stream) {
    const float* img  = (const float*)d_in[0];
    const float* Kern = (const float*)d_in[1];
    float* out        = (float*)d_out;

    if (ws_size >= (size_t)PADN * sizeof(unsigned short)) {
        unsigned short* gpad = (unsigned short*)d_ws;
        pad_kernel<<<(PADN + 255) / 256, 256, 0, stream>>>(img, gpad, out);
        reblur_kernel<<<1024, 128, 0, stream>>>(gpad, Kern, out);
    } else {
        reblur_naive<<<768, 256, 0, stream>>>(img, Kern, out);
    }
}

// Round 6
// 145.716 us; speedup vs baseline: 2.0691x; 2.0691x over previous
//
#include <hip/hip_runtime.h>

#define HH 512
#define WW 512
#define PD 544                          // 512 + 2*16
#define PADN (3 * PD * PD)              // 887808 bf16 elements
#define OUTN (3 * HH * WW)
#define NB 128
#define KSTR 16384                      // 128*128 floats between taps

// ---------------- pad + out-zero: fp32 img -> bf16 edge-padded ----------------
__global__ __launch_bounds__(256) void pad_kernel(const float* __restrict__ img,
                                                  unsigned short* __restrict__ gpad,
                                                  float* __restrict__ out) {
    int idx = blockIdx.x * 256 + threadIdx.x;
    if (idx < OUTN) out[idx] = 0.0f;           // zero the atomic target
    if (idx >= PADN) return;
    int c  = idx / (PD * PD);
    int r  = idx - c * (PD * PD);
    int py = r / PD;
    int px = r - py * PD;
    int iy = min(max(py - 16, 0), HH - 1);
    int ix = min(max(px - 16, 0), WW - 1);
    union { float f; unsigned u; } v;
    v.f = img[(c * HH + iy) * WW + ix];
    unsigned u = v.u + 0x7FFFu + ((v.u >> 16) & 1u);   // RNE bf16
    gpad[idx] = (unsigned short)(u >> 16);
}

// ---- async global->LDS (wave-uniform LDS base; HW puts lane i at base+i*size) ----
__device__ __forceinline__ void async16u(const unsigned short* g, unsigned short* l) {
    __builtin_amdgcn_global_load_lds((const __attribute__((address_space(1))) void*)g,
                                     (__attribute__((address_space(3))) void*)l, 16, 0, 0);
}
__device__ __forceinline__ float bflo(unsigned d) { union { unsigned u; float f; } x; x.u = d << 16;         return x.f; }
__device__ __forceinline__ float bfhi(unsigned d) { union { unsigned u; float f; } x; x.u = d & 0xFFFF0000u; return x.f; }

// ---------------- main kernel ----------------
// Grid = 2 u-chunks x 128 h x 2 wt = 512 blocks (exactly 2/CU) of 256 thr
// (4 waves, wave = dy). Lane owns (wb, dy, 3c, 4oj) = 12 accumulators.
// WEIGHTS: loaded global->register directly (L2/L3-resident tensor), double-
// buffered wA/wB one full iteration ahead -- no LDS, no barrier dependency,
// ~300cyc latency hidden under ~1300cyc compute. Unroll-2 via TEXTUAL macro
// (round-2/5 lesson: no dynamic indexing, no lambdas/references -> no scratch).
// IMAGE: bf16 rows in an 8-slot LDS ring via global_load_lds; window read =
// 9 ds_read_b64 per channel (8B/lane stride, near-conflict-free per round 4).
// One new row x 3c staged per iter by wave (tt&3). Sync per iter: own-stage
// s_waitcnt vmcnt(0) + one s_barrier. u-chunks combine via atomicAdd.
// LDS = 13.8 KB; __launch_bounds__(256,2) -> 256-VGPR cap, live set ~140.
__global__ __launch_bounds__(256, 2) void reblur_kernel(const unsigned short* __restrict__ gpad,
                                                        const float* __restrict__ Kern,
                                                        float* __restrict__ out) {
    __shared__ unsigned short s_img[8][3][288];   // 13824 B, ring over padded row

    const int lane = threadIdx.x & 63;
    const int dy   = threadIdx.x >> 6;            // wave id 0..3
    const int uq   = blockIdx.x >> 8;             // u-chunk 0..1
    const int bb   = blockIdx.x & 255;
    const int h    = bb >> 1;                     // 0..127
    const int wt   = bb & 1;                      // 0..1
    const int ua   = 17 * uq;                     // chunk start u
    const int n    = 17 - uq;                     // chunk length (17 or 16)
    const int kofs = h * NB + wt * 64 + lane;     // per-lane weight dword offset

    // ---- prologue: wave dy stages image row 4h+ua+dy (x3 channels); all waves
    //      load weight row u=ua into wA ----
    if (lane < 36) {
        const int r = 4 * h + ua + dy;
#pragma unroll
        for (int c = 0; c < 3; ++c)
            async16u(gpad + ((size_t)(c * PD + r) * PD + 256 * wt) + 8 * lane,
                     &s_img[r & 7][c][0]);
    }
    float wA[33], wB[33];
#pragma unroll
    for (int v = 0; v < 33; ++v)
        wA[v] = Kern[(size_t)(ua * 33 + v) * KSTR + kofs];

    float acc[3][4];
#pragma unroll
    for (int c = 0; c < 3; ++c)
#pragma unroll
        for (int oj = 0; oj < 4; ++oj) acc[c][oj] = 0.0f;

// One pipelined iteration. WCUR: weights for u=ua+tt (in regs); WNXT: buffer
// to receive u=ua+tt+1. All array indices compile-time constants.
#define R6_ITER(WCUR, WNXT, TT)                                                  \
    {                                                                            \
        const int tt = (TT);                                                     \
        asm volatile("s_waitcnt vmcnt(0)" ::: "memory");                         \
        __builtin_amdgcn_s_barrier();                                            \
        if (tt + 1 < n) {                                                        \
            const int un = ua + tt + 1;                                          \
            _Pragma("unroll")                                                    \
            for (int v = 0; v < 33; ++v)                                         \
                WNXT[v] = Kern[(size_t)(un * 33 + v) * KSTR + kofs];             \
            if (dy == (tt & 3) && lane < 36) {                                   \
                const int r = 4 * h + ua + tt + 4;                               \
                _Pragma("unroll")                                                \
                for (int c = 0; c < 3; ++c)                                      \
                    async16u(gpad + ((size_t)(c * PD + r) * PD + 256 * wt) + 8 * lane, \
                             &s_img[r & 7][c][0]);                               \
            }                                                                    \
        }                                                                        \
        const int slot = (4 * h + ua + tt + dy) & 7;                             \
        _Pragma("unroll")                                                        \
        for (int c = 0; c < 3; ++c) {                                            \
            float wf[36];                                                        \
            const unsigned short* sp = &s_img[slot][c][4 * lane];                \
            _Pragma("unroll")                                                    \
            for (int j = 0; j < 9; ++j) {                                        \
                const uint2 dd = *(const uint2*)(sp + 4 * j);                    \
                wf[4 * j + 0] = bflo(dd.x);                                      \
                wf[4 * j + 1] = bfhi(dd.x);                                      \
                wf[4 * j + 2] = bflo(dd.y);                                      \
                wf[4 * j + 3] = bfhi(dd.y);                                      \
            }                                                                    \
            _Pragma("unroll")                                                    \
            for (int v = 0; v < 33; ++v) {                                       \
                _Pragma("unroll")                                                \
                for (int oj = 0; oj < 4; ++oj)                                   \
                    acc[c][oj] = fmaf(wf[v + oj], WCUR[v], acc[c][oj]);          \
            }                                                                    \
        }                                                                        \
    }

    int t = 0;
#pragma unroll 1
    for (; t + 1 < n; t += 2) {
        R6_ITER(wA, wB, t);
        R6_ITER(wB, wA, t + 1);
    }
    if (t < n) {           // n odd (chunk 0): tail iter computes with wA
        R6_ITER(wA, wB, t);
    }
#undef R6_ITER

    // ---- epilogue: 2 u-chunks accumulate into the pad_kernel-zeroed output ----
    const int xb = 4 * (wt * 64 + lane);
#pragma unroll
    for (int c = 0; c < 3; ++c) {
        float* op = out + (size_t)(c * HH + 4 * h + dy) * WW + xb;
#pragma unroll
        for (int oj = 0; oj < 4; ++oj) atomicAdd(op + oj, acc[c][oj]);
    }
}

// ---------------- fallback (ws too small): naive but correct ----------------
__global__ __launch_bounds__(256) void reblur_naive(const float* __restrict__ img,
                                                    const float* __restrict__ Kern,
                                                    float* __restrict__ out) {
    const int lane = threadIdx.x & 63;
    const int dy   = threadIdx.x >> 6;
    const int c    = blockIdx.x >> 8;
    const int bb   = blockIdx.x & 255;
    const int h    = bb >> 1;
    const int wt   = bb & 1;
    const int wb   = wt * 64 + lane;
    const int y    = 4 * h + dy;

    float acc[4] = {0.f, 0.f, 0.f, 0.f};
    const float* kb = Kern + h * NB + wb;
#pragma unroll 1
    for (int u = 0; u < 33; ++u) {
        const int iy = min(max(y + u - 16, 0), HH - 1);
        float row[36];
#pragma unroll
        for (int e = 0; e < 36; ++e) {
            const int ix = min(max(4 * wb + e - 16, 0), WW - 1);
            row[e]       = img[(c * HH + iy) * WW + ix];
        }
#pragma unroll
        for (int v = 0; v < 33; ++v) {
            const float w = kb[(u * 33 + v) * KSTR];
#pragma unroll
            for (int oj = 0; oj < 4; ++oj)
                acc[oj] = fmaf(row[v + oj], w, acc[oj]);
        }
    }
    float4 o;
    o.x = acc[0]; o.y = acc[1]; o.z = acc[2]; o.w = acc[3];
    *reinterpret_cast<float4*>(out + (size_t)(c * HH + y) * WW + 4 * wb) = o;
}

extern "C" void kernel_launch(void* const* d_in, const int* in_sizes, int n_in,
                              void* d_out, int out_size, void* d_ws, size_t ws_size,
                              hipStream_t stream) {
    const float* img  = (const float*)d_in[0];
    const float* Kern = (const float*)d_in[1];
    float* out        = (float*)d_out;

    if (ws_size >= (size_t)PADN * sizeof(unsigned short)) {
        unsigned short* gpad = (unsigned short*)d_ws;
        pad_kernel<<<(PADN + 255) / 256, 256, 0, stream>>>(img, gpad, out);
        reblur_kernel<<<512, 256, 0, stream>>>(gpad, Kern, out);
    } else {
        reblur_naive<<<768, 256, 0, stream>>>(img, Kern, out);
    }
}